// Round 5
// baseline (304.960 us; speedup 1.0000x reference)
//
#include <hip/hip_runtime.h>
#include <math.h>

#define C_LEN 2048
#define HALF  1024
#define OUTD  1536
#define NPIX  32768

// ======================= uv + twiddle-table precompute ======================
__device__ __forceinline__ int SWZ(int idx) { return idx ^ ((idx >> 5) & 31); }

template<int DIR>
__device__ void fft2048(float* r0, float* i0, float* r1, float* i1, int t) {
    float *sr = r0, *si = i0, *dr = r1, *di = i1;
    const float TW = (float)DIR * 6.283185307179586f / 2048.0f;
    const float FD = (float)DIR;
    __syncthreads();
    #pragma unroll
    for (int b = 0; b < 4; ++b) {
        int t2 = t + b * 256;
        float ar = sr[SWZ(t2)],        ai = si[SWZ(t2)];
        float br = sr[SWZ(t2 + 1024)], bi = si[SWZ(t2 + 1024)];
        float sn, cs;
        sincosf(TW * (float)t2, &sn, &cs);
        float vr = ar - br, vi = ai - bi;
        int w0 = 2 * t2;
        dr[SWZ(w0)]     = ar + br;
        di[SWZ(w0)]     = ai + bi;
        dr[SWZ(w0 + 1)] = cs * vr - sn * vi;
        di[SWZ(w0 + 1)] = cs * vi + sn * vr;
    }
    { float* tp; tp = sr; sr = dr; dr = tp; tp = si; si = di; di = tp; }
    #pragma unroll
    for (int m = 2; m <= 512; m *= 4) {
        __syncthreads();
        #pragma unroll
        for (int b = 0; b < 2; ++b) {
            int t2 = t + b * 256;
            int jm = t2 & ~(m - 1);
            float a0r = sr[SWZ(t2)],        a0i = si[SWZ(t2)];
            float a1r = sr[SWZ(t2 + 512)],  a1i = si[SWZ(t2 + 512)];
            float a2r = sr[SWZ(t2 + 1024)], a2i = si[SWZ(t2 + 1024)];
            float a3r = sr[SWZ(t2 + 1536)], a3i = si[SWZ(t2 + 1536)];
            float s0r = a0r + a2r, s0i = a0i + a2i;
            float d0r = a0r - a2r, d0i = a0i - a2i;
            float s1r = a1r + a3r, s1i = a1i + a3i;
            float d1r = a1r - a3r, d1i = a1i - a3i;
            float A0r = s0r + s1r, A0i = s0i + s1i;
            float A2r = s0r - s1r, A2i = s0i - s1i;
            float A1r = d0r - FD * d1i, A1i = d0i + FD * d1r;
            float A3r = d0r + FD * d1i, A3i = d0i - FD * d1r;
            float s1w, c1w;
            sincosf(TW * (float)jm, &s1w, &c1w);
            float c2w = c1w * c1w - s1w * s1w, s2w = 2.0f * c1w * s1w;
            float c3w = c1w * c2w - s1w * s2w, s3w = c1w * s2w + s1w * c2w;
            int wb = t2 + 3 * jm;
            dr[SWZ(wb)]         = A0r;
            di[SWZ(wb)]         = A0i;
            dr[SWZ(wb + m)]     = c1w * A1r - s1w * A1i;
            di[SWZ(wb + m)]     = c1w * A1i + s1w * A1r;
            dr[SWZ(wb + 2 * m)] = c2w * A2r - s2w * A2i;
            di[SWZ(wb + 2 * m)] = c2w * A2i + s2w * A2r;
            dr[SWZ(wb + 3 * m)] = c3w * A3r - s3w * A3i;
            di[SWZ(wb + 3 * m)] = c3w * A3i + s3w * A3r;
        }
        { float* tp; tp = sr; sr = dr; dr = tp; tp = si; si = di; di = tp; }
    }
    __syncthreads();
}

__global__ __launch_bounds__(256)
void uv_kernel(const float* __restrict__ w1, const float* __restrict__ w2,
               float4* __restrict__ uv, float2* __restrict__ tab1,
               float2* __restrict__ tab2) {
    __shared__ float r0[C_LEN], i0[C_LEN], r1[C_LEN], i1[C_LEN];
    int t = threadIdx.x;
    #pragma unroll
    for (int k = 0; k < 8; ++k) {
        int e = t + k * 256;
        r0[SWZ(e)] = w1[e] * w2[e];
        i0[SWZ(e)] = 0.0f;
    }
    fft2048<-1>(r0, i0, r1, i1, t);
    #pragma unroll
    for (int b = 0; b < 4; ++b) {
        int k = t + b * 256;
        float w1r = r0[SWZ(k)],        w1i = i0[SWZ(k)];
        float w2r = r0[SWZ(k + 1024)], w2i = i0[SWZ(k + 1024)];
        float Sr = (w1r + w2r) * (1.0f / 4096.0f);
        float Si = (w1i + w2i) * (1.0f / 4096.0f);
        float Dr = (w1r - w2r) * (1.0f / 4096.0f);
        float Di = (w1i - w2i) * (1.0f / 4096.0f);
        float sn, cs;
        sincosf((6.283185307179586f / 2048.0f) * (float)k, &sn, &cs);
        float Er = cs * Dr - sn * Di, Ei = cs * Di + sn * Dr;
        float Fr = cs * Dr + sn * Di, Fi = cs * Di - sn * Dr;
        uv[k] = make_float4(Sr - Ei, Si + Er, Sr + Fi, Si - Fr);
    }
    // forward twiddle tables (inverse = conj, applied in-register)
    // tab1[t][c] = exp(-2*pi*i*t*c/1024), t in [0,64), c in [0,16)
    #pragma unroll
    for (int b = 0; b < 4; ++b) {
        int e = t + b * 256;
        int row = e >> 4, c = e & 15;
        float sn, cs;
        sincosf((-6.283185307179586f / 1024.0f) * (float)(row * c), &sn, &cs);
        tab1[e] = make_float2(cs, sn);
    }
    // tab2[f][m] = exp(-2*pi*i*f*m/64), f in [0,4), m in [0,16)
    if (t < 64) {
        int f = t >> 4, m = t & 15;
        float sn, cs;
        sincosf((-6.283185307179586f / 64.0f) * (float)(f * m), &sn, &cs);
        tab2[t] = make_float2(cs, sn);
    }
}

// ======================= in-place register FFT16 ============================
__device__ __forceinline__ void cm(float& or_, float& oi_, float ar, float ai,
                                   float br, float bi) {
    or_ = ar * br - ai * bi;
    oi_ = ar * bi + ai * br;
}

// In-place 16-pt DFT (sign S). Output digit-swapped:
//   slot[4*(k&3) + (k>>2)] = X[k],  X[k] = sum_n x[n] e^{S*2*pi*i*n*k/16}
template<int S>
__device__ __forceinline__ void fft16_ip(float* xr, float* xi) {
    const float FS = (float)S;
    const float C1 = 0.9238795325112867f;
    const float S1 = 0.3826834323650898f;
    const float R2 = 0.7071067811865476f;
    #pragma unroll
    for (int n0 = 0; n0 < 4; ++n0) {
        float a0r = xr[n0],      a0i = xi[n0];
        float a1r = xr[n0 + 4],  a1i = xi[n0 + 4];
        float a2r = xr[n0 + 8],  a2i = xi[n0 + 8];
        float a3r = xr[n0 + 12], a3i = xi[n0 + 12];
        float t0r = a0r + a2r, t0i = a0i + a2i;
        float t1r = a0r - a2r, t1i = a0i - a2i;
        float t2r = a1r + a3r, t2i = a1i + a3i;
        float t3r = a1r - a3r, t3i = a1i - a3i;
        float y1r = t1r - FS * t3i, y1i = t1i + FS * t3r;
        float y2r = t0r - t2r,      y2i = t0i - t2i;
        float y3r = t1r + FS * t3i, y3i = t1i - FS * t3r;
        xr[n0] = t0r + t2r;  xi[n0] = t0i + t2i;
        if (n0 == 0) {
            xr[4]  = y1r; xi[4]  = y1i;
            xr[8]  = y2r; xi[8]  = y2i;
            xr[12] = y3r; xi[12] = y3i;
        } else if (n0 == 1) {
            cm(xr[5],  xi[5],  y1r, y1i, C1,  FS * S1);
            cm(xr[9],  xi[9],  y2r, y2i, R2,  FS * R2);
            cm(xr[13], xi[13], y3r, y3i, S1,  FS * C1);
        } else if (n0 == 2) {
            cm(xr[6],  xi[6],  y1r, y1i, R2,  FS * R2);
            xr[10] = -FS * y2i;  xi[10] = FS * y2r;
            cm(xr[14], xi[14], y3r, y3i, -R2, FS * R2);
        } else {
            cm(xr[7],  xi[7],  y1r, y1i, S1,  FS * C1);
            cm(xr[11], xi[11], y2r, y2i, -R2, FS * R2);
            cm(xr[15], xi[15], y3r, y3i, -C1, -FS * S1);
        }
    }
    #pragma unroll
    for (int k0 = 0; k0 < 4; ++k0) {
        float b0r = xr[4 * k0],     b0i = xi[4 * k0];
        float b1r = xr[4 * k0 + 1], b1i = xi[4 * k0 + 1];
        float b2r = xr[4 * k0 + 2], b2i = xi[4 * k0 + 2];
        float b3r = xr[4 * k0 + 3], b3i = xi[4 * k0 + 3];
        float t0r = b0r + b2r, t0i = b0i + b2i;
        float t1r = b0r - b2r, t1i = b0i - b2i;
        float t2r = b1r + b3r, t2i = b1i + b3i;
        float t3r = b1r - b3r, t3i = b1i - b3i;
        xr[4 * k0]     = t0r + t2r;      xi[4 * k0]     = t0i + t2i;
        xr[4 * k0 + 1] = t1r - FS * t3i; xi[4 * k0 + 1] = t1i + FS * t3r;
        xr[4 * k0 + 2] = t0r - t2r;      xi[4 * k0 + 2] = t0i - t2i;
        xr[4 * k0 + 3] = t1r + FS * t3i; xi[4 * k0 + 3] = t1i - FS * t3r;
    }
}

// Table twiddle + transposed LDS store. tabrow = this lane's 16 fwd twiddles;
// CONJ=1 conjugates them (inverse pass). Reads digit-swapped slot p.
template<int CONJ>
__device__ __forceinline__ void tw_store_tab(const float* vr, const float* vi,
                                             float2* row, int xorv,
                                             const float2* __restrict__ tabrow) {
    const float4* t4 = reinterpret_cast<const float4*>(tabrow);
    #pragma unroll
    for (int j = 0; j < 8; ++j) {
        float4 w2v = t4[j];                 // twiddles for c=2j (x,y), 2j+1 (z,w)
        #pragma unroll
        for (int h = 0; h < 2; ++h) {
            int c = 2 * j + h;
            int p = ((c & 3) << 2) | (c >> 2);
            float wr = h ? w2v.z : w2v.x;
            float wi = h ? w2v.w : w2v.y;
            if (CONJ) wi = -wi;
            float x = vr[p] * wr - vi[p] * wi;
            float y = vr[p] * wi + vi[p] * wr;
            row[c ^ xorv] = make_float2(x, y);
        }
    }
}

// ======================= main kernel: wave per pixel, no barriers ===========
// Each wave owns a private 1024-float2 LDS slice; all LDS deps are
// intra-wave (in-order DS + compiler lgkmcnt), so NO __syncthreads anywhere.
// FFT1024 = FFT16(regs over a) -> *W1024^{tc} -> T1 -> FFT16(regs over e)
//           -> *W64^{fm} -> T2 -> FFT4(regs over f).  n=64a+b; b=4e+f;
//           k = c + 16m + 256p.
__global__ __launch_bounds__(256, 8)
void conv256(const float* __restrict__ x, const float4* __restrict__ uv,
             const float2* __restrict__ tab1, const float2* __restrict__ tab2,
             float2* __restrict__ out) {
    __shared__ float2 ldsAll[4 * HALF];
    const int tid = threadIdx.x;
    const int t   = tid & 63;
    const int wid = tid >> 6;
    float2* lds = ldsAll + (wid << 10);
    const size_t pix = ((size_t)blockIdx.x << 2) + wid;
    const float2* xp = reinterpret_cast<const float2*>(x) + pix * (size_t)HALF;

    float vr[16], vi[16];
    #pragma unroll
    for (int a = 0; a < 16; ++a) {
        float2 z = xp[(a << 6) + t];
        vr[a] = z.x; vi[a] = z.y;
    }

    // ---------------- forward ----------------
    fft16_ip<-1>(vr, vi);
    tw_store_tab<0>(vr, vi, lds + (t << 4), t & 15, tab1 + (t << 4));  // T1 w
    {
        const int f = t & 3, c = t >> 2;
        #pragma unroll
        for (int e = 0; e < 16; ++e) {                                 // T1 r
            int row = (e << 2) + f;
            float2 z = lds[(row << 4) + (c ^ (row & 15))];
            vr[e] = z.x; vi[e] = z.y;
        }
        fft16_ip<-1>(vr, vi);
        tw_store_tab<0>(vr, vi, lds + (t << 4), c, tab2 + (f << 4));   // T2 w
    }
    {
        const int q = t & 3, c = t >> 2;
        float dr[16], di[16];
        #pragma unroll
        for (int f = 0; f < 4; ++f) {
            #pragma unroll
            for (int s = 0; s < 4; ++s) {                              // T2 r
                int wrow = (c << 2) + f;
                float2 z = lds[(wrow << 4) + (((q << 2) + s) ^ c)];
                dr[f * 4 + s] = z.x; di[f * 4 + s] = z.y;
            }
        }
        #pragma unroll
        for (int s = 0; s < 4; ++s) {                                  // FFT4 f
            float ar = dr[0 + s],  ai = di[0 + s];
            float br = dr[4 + s],  bi = di[4 + s];
            float cr = dr[8 + s],  ci = di[8 + s];
            float er = dr[12 + s], ei = di[12 + s];
            float t0r = ar + cr, t0i = ai + ci;
            float t1r = ar - cr, t1i = ai - ci;
            float t2r = br + er, t2i = bi + ei;
            float t3r = br - er, t3i = bi - ei;
            int kb = c + (((q << 2) + s) << 4);
            lds[kb]       = make_float2(t0r + t2r, t0i + t2i);         // p=0
            lds[kb + 256] = make_float2(t1r + t3i, t1i - t3r);         // p=1
            lds[kb + 512] = make_float2(t0r - t2r, t0i - t2i);         // p=2
            lds[kb + 768] = make_float2(t1r - t3i, t1i + t3r);         // p=3
        }
    }

    // ------------- middle (rfft unpack * Wf * repack) ------------
    #pragma unroll
    for (int a = 0; a < 16; ++a) {
        int k = (a << 6) + t;
        float2 Za = lds[k];
        float2 Zm = lds[(HALF - k) & (HALF - 1)];
        float4 u  = uv[k];
        float Ar = Za.x + Zm.x, Ai = Za.y - Zm.y;
        float Br = Za.x - Zm.x, Bi = Za.y + Zm.y;
        vr[a] = Ar * u.x - Ai * u.y + Br * u.z - Bi * u.w;
        vi[a] = Ar * u.y + Ai * u.x + Br * u.w + Bi * u.z;
    }

    // ---------------- inverse ----------------
    fft16_ip<1>(vr, vi);
    tw_store_tab<1>(vr, vi, lds + (t << 4), t & 15, tab1 + (t << 4));  // T4 w
    {
        const int f = t & 3, c = t >> 2;
        #pragma unroll
        for (int e = 0; e < 16; ++e) {                                 // T4 r
            int row = (e << 2) + f;
            float2 z = lds[(row << 4) + (c ^ (row & 15))];
            vr[e] = z.x; vi[e] = z.y;
        }
        fft16_ip<1>(vr, vi);
        tw_store_tab<1>(vr, vi, lds + (t << 4), c, tab2 + (f << 4));   // T5 w
    }
    {
        const int q = t & 3, c = t >> 2;
        float dr[16], di[16];
        #pragma unroll
        for (int f = 0; f < 4; ++f) {
            #pragma unroll
            for (int s = 0; s < 4; ++s) {                              // T5 r
                int wrow = (c << 2) + f;
                float2 z = lds[(wrow << 4) + (((q << 2) + s) ^ c)];
                dr[f * 4 + s] = z.x; di[f * 4 + s] = z.y;
            }
        }
        float2* op = out + pix * (size_t)(OUTD / 2);
        #pragma unroll
        for (int s = 0; s < 4; ++s) {                                  // FFT4 i
            float ar = dr[0 + s],  ai = di[0 + s];
            float br = dr[4 + s],  bi = di[4 + s];
            float cr = dr[8 + s],  ci = di[8 + s];
            float er = dr[12 + s], ei = di[12 + s];
            float t0r = ar + cr, t0i = ai + ci;
            float t1r = ar - cr, t1i = ai - ci;
            float t2r = br + er, t2i = bi + ei;
            float t3r = br - er, t3i = bi - ei;
            int nb = c + (((q << 2) + s) << 4);
            op[nb]       = make_float2(t0r + t2r, t0i + t2i);          // p=0
            op[nb + 256] = make_float2(t1r - t3i, t1i + t3r);          // p=1
            op[nb + 512] = make_float2(t0r - t2r, t0i - t2i);          // p=2
            // p=3 (n >= 768) not stored
        }
    }
}

extern "C" void kernel_launch(void* const* d_in, const int* in_sizes, int n_in,
                              void* d_out, int out_size, void* d_ws, size_t ws_size,
                              hipStream_t stream) {
    const float* x  = (const float*)d_in[0];
    const float* w1 = (const float*)d_in[1];
    const float* w2 = (const float*)d_in[2];
    float2* out = (float2*)d_out;
    char* ws = (char*)d_ws;
    float4* uv   = (float4*)ws;                    // 16 KB
    float2* tab1 = (float2*)(ws + 16384);          // 8 KB
    float2* tab2 = (float2*)(ws + 16384 + 8192);   // 512 B

    hipLaunchKernelGGL(uv_kernel, dim3(1), dim3(256), 0, stream,
                       w1, w2, uv, tab1, tab2);
    hipLaunchKernelGGL(conv256, dim3(NPIX / 4), dim3(256), 0, stream,
                       x, uv, tab1, tab2, out);
}